// Round 14
// baseline (308.977 us; speedup 1.0000x reference)
//
#include <hip/hip_runtime.h>

#define DIM     128
#define NCODES  1024
#define TILE_M  64
#define FLAGThr 0.005f       // e-side-only Hoeffding ~12.8σ (x split; 4-bit pack err 3e-5)
#define RPB     4            // refine rows per block (r10-proven)
#define RGRID   1024         // refine grid (r10-proven)

typedef __attribute__((ext_vector_type(8))) _Float16 half8;
typedef __attribute__((ext_vector_type(4))) _Float16 half4;
typedef __attribute__((ext_vector_type(4))) float    f32x4;

#define AS1 __attribute__((address_space(1)))
#define AS3 __attribute__((address_space(3)))

// ws layout:
//      0 : e2d    (1024 double)          8 KB
//   8192 : e2f    (1024 float)           4 KB
//  12288 : eh     (1024*128 _Float16)  256 KB
// 274432 : embedT (128*1024 float)     512 KB
// 798720 : cnt    (int)
// 798976 : list   (65536 int)          256 KB

// -------- setup (r10 form): e2 f32/f64, eh fp16, embedT transpose ---------
__global__ __launch_bounds__(256) void setup_kernel(
    const float* __restrict__ embed, double* __restrict__ e2d,
    float* __restrict__ e2f, _Float16* __restrict__ eh,
    float* __restrict__ embedT, int* __restrict__ cnt)
{
  __shared__ float tile[64][132];            // 132: 16B-aligned rows
  __shared__ double psum[4][64];
  if (blockIdx.x == 0 && threadIdx.x == 0) *cnt = 0;
  const int c0 = blockIdx.x * 64;            // 16 blocks x 64 codes
  const int t  = threadIdx.x;

  const f32x4* E4 = (const f32x4*)(embed + (size_t)c0 * DIM);
  #pragma unroll
  for (int i = 0; i < 8; ++i) {
    int e = t + i * 256;                     // 2048 float4s = 64x128
    int r = e >> 5, c4 = e & 31;
    f32x4 v = E4[e];
    *(f32x4*)&tile[r][c4 * 4] = v;
    half4 h;
    h[0] = (_Float16)v[0]; h[1] = (_Float16)v[1];
    h[2] = (_Float16)v[2]; h[3] = (_Float16)v[3];
    *(half4*)&eh[(size_t)(c0 + r) * DIM + c4 * 4] = h;
  }
  __syncthreads();

  // e2: 4 threads per code, 32 dims each
  {
    int r = t & 63, part = t >> 6;
    double s = 0.0;
    #pragma unroll
    for (int k = 0; k < 32; ++k) {
      float v = tile[r][part * 32 + k];
      s += (double)v * v;
    }
    psum[part][r] = s;
  }
  __syncthreads();
  if (t < 64) {
    double s = psum[0][t] + psum[1][t] + psum[2][t] + psum[3][t];
    e2d[c0 + t] = s;
    e2f[c0 + t] = (float)s;
  }

  // embedT[k][c0+c] = tile[c][k]; coalesced 256B segments per k-row
  #pragma unroll
  for (int i = 0; i < 32; ++i) {
    int idx = t + i * 256;                   // 8192 = 128k x 64c
    int k = idx >> 6, c = idx & 63;
    embedT[(size_t)k * NCODES + c0 + c] = tile[c][k];
  }
}

// -------- pass1 v16: v13 core + SPLIT-FP16 A (x=hi+lo) + 4-bit pack -------
// acc = (x_hi+x_lo).e_fp16 - 0.5*e2 - 16 via TWO chained MFMA passes
// (Dekker split: x-side quantization error eliminated to 2^-23). Index
// packed in low 4 mantissa bits only (ch; w,rl are lane constants) ->
// pack err 15 ulps ~ 3e-5 (was 1023 ulps ~ 2e-3). Merge carries explicit
// (val,code). Remaining score error: e-side fp16 sigma ~3.9e-4 ->
// FLAGThr 0.005 = 12.8 sigma -> flagged-row count n shrinks ~3.6x ->
// refine2 cost /3.6 (the dominant non-pass1 term).
// Pipeline = v13 verbatim (proven 44.3us clean): wave-private 3-deep
// gload_lds, counted vmcnt, zero loop barriers, swizzle involution.
// Regs ~210 < 256 cap (256,2); LDS 69.9KB -> 2 blocks/CU (same as v13).
__global__ __launch_bounds__(256, 2) void pass1_kernel(
    const float* __restrict__ x, const float* __restrict__ embed,
    const _Float16* __restrict__ eh, const float* __restrict__ e2f,
    float* __restrict__ outQ, float* __restrict__ outIdx,
    int* __restrict__ cnt, int* __restrict__ list)
{
  __shared__ __align__(16) _Float16 xh[TILE_M * 136];      // 17408 B
  __shared__ __align__(16) unsigned char bbuf[4][3][4096]; // 49152 B
  __shared__ float rb_best[4][TILE_M];
  __shared__ float rb_sec [4][TILE_M];
  __shared__ int   rb_bidx[4][TILE_M];
  __shared__ int   fidx[TILE_M];

  const int tid  = threadIdx.x;
  const int row0 = blockIdx.x * TILE_M;
  const int l  = tid & 63, w = tid >> 6;
  const int rl = l & 15,  q = l >> 4;

#define STAGE_W(CH)                                                           \
  {                                                                           \
    const char* ebase = (const char*)eh + ((size_t)(CH) * 64 + w * 16) * 256; \
    unsigned char* buf = &bbuf[w][(CH) % 3][0];                               \
    _Pragma("unroll")                                                         \
    for (int j = 0; j < 4; ++j) {                                             \
      int u  = j * 64 + l;                  /* 16B-unit 0..255 = 16r x 16c */ \
      int rr = u >> 4, cc = u & 15;                                           \
      const char* src = ebase + rr * 256 + ((cc ^ rr) * 16);                  \
      __builtin_amdgcn_global_load_lds(                                       \
          (AS1 void*)src,                                                     \
          (AS3 void*)(buf + j * 1024), 16, 0, 0);                             \
    }                                                                         \
  }

  // ---- prologue ----
  float vin[16];                             // code(ch) = ch*64 + w*16 + rl
  #pragma unroll
  for (int g = 0; g < 16; ++g)
    vin[g] = fmaf(-0.5f, e2f[g * 64 + w * 16 + rl], -16.0f);

  // x tile (64x128 f32 -> fp16 hi), coalesced (v13 path)
  {
    const f32x4* x4 = (const f32x4*)(x + (size_t)row0 * DIM);
    #pragma unroll
    for (int i = 0; i < 8; ++i) {
      int e = tid + i * 256;                 // 2048 float4s
      int r = e >> 5, c4 = e & 31;
      f32x4 v = x4[e];
      half4 h;
      h[0] = (_Float16)v[0]; h[1] = (_Float16)v[1];
      h[2] = (_Float16)v[2]; h[3] = (_Float16)v[3];
      *(half4*)&xh[r * 136 + c4 * 4] = h;
    }
  }
  __syncthreads();

  half8 afrag[4][4];
  #pragma unroll
  for (int m = 0; m < 4; ++m)
    #pragma unroll
    for (int ks = 0; ks < 4; ++ks)
      afrag[m][ks] = *(const half8*)&xh[(m * 16 + rl) * 136 + ks * 32 + q * 8];

  // a_lo[m][ks] = fp16(x - (float)hi), x re-read from global (L2/L3-hot:
  // this block just streamed the same 32KB tile). Dekker split: hi+lo
  // carries ~22 bits of x -> x-side quantization error eliminated.
  half8 alo[4][4];
  #pragma unroll
  for (int m = 0; m < 4; ++m)
    #pragma unroll
    for (int ks = 0; ks < 4; ++ks) {
      const float* xp = x + (size_t)(row0 + m * 16 + rl) * DIM + ks * 32 + q * 8;
      f32x4 a = *(const f32x4*)xp;
      f32x4 b = *(const f32x4*)(xp + 4);
      half8 h = afrag[m][ks];
      half8 lo;
      lo[0] = (_Float16)(a[0] - (float)h[0]);
      lo[1] = (_Float16)(a[1] - (float)h[1]);
      lo[2] = (_Float16)(a[2] - (float)h[2]);
      lo[3] = (_Float16)(a[3] - (float)h[3]);
      lo[4] = (_Float16)(b[0] - (float)h[4]);
      lo[5] = (_Float16)(b[1] - (float)h[5]);
      lo[6] = (_Float16)(b[2] - (float)h[6]);
      lo[7] = (_Float16)(b[3] - (float)h[7]);
      alo[m][ks] = lo;
    }

  float bestp[16], secp[16];
  #pragma unroll
  for (int s = 0; s < 16; ++s) { bestp[s] = -3.0e38f; secp[s] = -3.3e38f; }

  // all prologue VMEM retired -> stage counting is clean
  asm volatile("s_waitcnt vmcnt(0)" ::: "memory");
  __builtin_amdgcn_sched_barrier(0);

  STAGE_W(0)
  STAGE_W(1)
  STAGE_W(2)

  // main loop: barrier-free; wave w owns codes [ch*64+w*16, +16)
  #pragma unroll
  for (int ch = 0; ch < 16; ++ch) {
    if (ch <= 13) {
      asm volatile("s_waitcnt vmcnt(8)" ::: "memory");
    } else if (ch == 14) {
      asm volatile("s_waitcnt vmcnt(4)" ::: "memory");
    } else {
      asm volatile("s_waitcnt vmcnt(0)" ::: "memory");
    }
    __builtin_amdgcn_sched_barrier(0);

    const unsigned char* bb = &bbuf[w][ch % 3][0];
    half8 bfrag[4];
    #pragma unroll
    for (int ks = 0; ks < 4; ++ks)
      bfrag[ks] = *(const half8*)(bb + rl * 256 + (((ks * 4 + q) ^ rl) * 16));

    const float vinit = vin[ch];
    #pragma unroll
    for (int m = 0; m < 4; ++m) {
      f32x4 acc = (f32x4){vinit, vinit, vinit, vinit};
      #pragma unroll
      for (int ks = 0; ks < 4; ++ks)   // lo pass first (smaller magnitudes)
        acc = __builtin_amdgcn_mfma_f32_16x16x32_f16(alo[m][ks], bfrag[ks], acc, 0, 0, 0);
      #pragma unroll
      for (int ks = 0; ks < 4; ++ks)   // hi pass
        acc = __builtin_amdgcn_mfma_f32_16x16x32_f16(afrag[m][ks], bfrag[ks], acc, 0, 0, 0);
      #pragma unroll
      for (int r = 0; r < 4; ++r) {
        const int s = m * 4 + r;
        // pack ONLY ch (4 bits): w,rl are lane constants, reconstructed at merge
        float scp = __int_as_float((__float_as_int(acc[r]) & ~15) | ch);
        secp[s]  = __builtin_amdgcn_fmed3f(scp, bestp[s], secp[s]);
        bestp[s] = fmaxf(bestp[s], scp);
      }
    }

    if (ch + 3 < 16) {
      asm volatile("s_waitcnt lgkmcnt(0)" ::: "memory");
      __builtin_amdgcn_sched_barrier(0);
      STAGE_W(ch + 3)
    }
  }
#undef STAGE_W

  // unpack (recover exact values + full codes), then explicit-index merge
  float bval[16], sval[16];
  int   bcode[16];
  #pragma unroll
  for (int s = 0; s < 16; ++s) {
    int bi = __float_as_int(bestp[s]);
    bval[s]  = __int_as_float(bi & ~15);
    bcode[s] = (bi & 15) * 64 + w * 16 + rl;
    sval[s]  = __int_as_float(__float_as_int(secp[s]) & ~15);
  }
  // merge across the 16 lanes of each quarter (same rows, different codes);
  // ties -> lower code (reference argmax semantics)
  #pragma unroll
  for (int off = 1; off < 16; off <<= 1) {
    #pragma unroll
    for (int s = 0; s < 16; ++s) {
      float ov = __shfl_xor(bval[s],  off, 16);
      int   oc = __shfl_xor(bcode[s], off, 16);
      float os = __shfl_xor(sval[s],  off, 16);
      bool take = (ov > bval[s]) || (ov == bval[s] && oc < bcode[s]);
      float lose = take ? bval[s] : ov;
      float cs   = take ? os : sval[s];
      bval[s]  = take ? ov : bval[s];
      bcode[s] = take ? oc : bcode[s];
      sval[s]  = fmaxf(cs, lose);
    }
  }
  if (rl == 0) {
    #pragma unroll
    for (int m = 0; m < 4; ++m)
      #pragma unroll
      for (int r = 0; r < 4; ++r) {
        int s = m * 4 + r;
        int row = m * 16 + q * 4 + r;
        rb_best[w][row] = bval[s];
        rb_bidx[w][row] = bcode[s];
        rb_sec [w][row] = sval[s];
      }
  }
  __syncthreads();

  // merge the 4 waves (disjoint code sets), emit index + flag near-ties
  if (tid < TILE_M) {
    float bv = rb_best[0][tid]; int bc = rb_bidx[0][tid]; float sv = rb_sec[0][tid];
    #pragma unroll
    for (int ww = 1; ww < 4; ++ww) {
      float ob = rb_best[ww][tid]; int oc = rb_bidx[ww][tid]; float os = rb_sec[ww][tid];
      bool take = (ob > bv) || (ob == bv && oc < bc);
      float lose = take ? bv : ob;
      float cs   = take ? os : sv;
      bv = take ? ob : bv;
      bc = take ? oc : bc;
      sv = fmaxf(cs, lose);
    }
    int grow = row0 + tid;
    outIdx[grow] = (float)bc;
    fidx[tid] = bc;
    if (bv - sv <= FLAGThr) {
      int p = atomicAdd(cnt, 1);
      list[p] = grow;
    }
  }
  __syncthreads();

  // gather quantize = embed[idx] (coalesced writes, L2-hot embed reads)
  {
    const f32x4* E4   = (const f32x4*)embed;
    f32x4*       out4 = (f32x4*)(outQ + (size_t)row0 * DIM);
    #pragma unroll
    for (int i = 0; i < 8; ++i) {
      int e = tid + i * 256;
      int r = e >> 5, c4 = e & 31;
      out4[e] = E4[fidx[r] * 32 + c4];
    }
  }
}

// -------- refine v2 (r10 form): coalesced f32 rescan via embedT, f64 ------
__global__ __launch_bounds__(256) void refine2_kernel(
    const float* __restrict__ x, const float* __restrict__ embed,
    const float* __restrict__ embedT,
    const double* __restrict__ e2d, const float* __restrict__ e2f,
    float* __restrict__ outQ, float* __restrict__ outIdx,
    const int* __restrict__ cnt, const int* __restrict__ list)
{
  __shared__ f32x4 xst[DIM];                 // xst[k][r]: k-th dim of row r
  __shared__ float rb1[RPB][4], rb2[RPB][4];
  __shared__ int   ri1[RPB][4], ri2[RPB][4];
  __shared__ int   cand[RPB][2];

  const int t = threadIdx.x;
  const int l = t & 63, w = t >> 6;
  const int n = *cnt;
  float* xsf = (float*)xst;

  for (int base = blockIdx.x * RPB; base < n; base += RGRID * RPB) {
    const int nr = min(RPB, n - base);
    // stage rows (transposed: xst[k][r])
    #pragma unroll
    for (int i = 0; i < 2; ++i) {
      int idx = t + i * 256;
      int r = idx >> 7, k = idx & 127;
      float v = 0.f;
      if (r < nr) v = x[(size_t)list[base + r] * DIM + k];
      xsf[k * RPB + r] = v;
    }
    __syncthreads();

    // thread t owns codes 4t..4t+3; fully coalesced embedT stream
    f32x4 dot[RPB];
    #pragma unroll
    for (int r = 0; r < RPB; ++r) dot[r] = (f32x4){0.f, 0.f, 0.f, 0.f};
    const f32x4* eT4 = (const f32x4*)embedT;
    #pragma unroll 4
    for (int k = 0; k < DIM; ++k) {
      f32x4 e4  = eT4[k * 256 + t];
      f32x4 xk4 = xst[k];
      #pragma unroll
      for (int r = 0; r < RPB; ++r) {
        dot[r][0] = fmaf(xk4[r], e4[0], dot[r][0]);
        dot[r][1] = fmaf(xk4[r], e4[1], dot[r][1]);
        dot[r][2] = fmaf(xk4[r], e4[2], dot[r][2]);
        dot[r][3] = fmaf(xk4[r], e4[3], dot[r][3]);
      }
    }

    // per-thread top-2 over its 4 codes, then wave + block merges
    #pragma unroll
    for (int r = 0; r < RPB; ++r) {
      float b1 = 3.4e38f, b2 = 3.4e38f; int i1 = 0, i2 = 0;
      #pragma unroll
      for (int j = 0; j < 4; ++j) {
        int c = 4 * t + j;
        float sc = fmaf(-2.0f, dot[r][j], e2f[c]);
        bool better = (sc < b1);                 // ties keep lower index
        float lv = better ? b1 : sc;  int li = better ? i1 : c;
        if (better) { b1 = sc; i1 = c; }
        bool t2 = (lv < b2) || (lv == b2 && li < i2);
        if (t2) { b2 = lv; i2 = li; }
      }
      #pragma unroll
      for (int off = 1; off < 64; off <<= 1) {
        float o1 = __shfl_xor(b1, off, 64); int oi1 = __shfl_xor(i1, off, 64);
        float o2 = __shfl_xor(b2, off, 64); int oi2 = __shfl_xor(i2, off, 64);
        bool take = (o1 < b1) || (o1 == b1 && oi1 < i1);
        float n1 = take ? o1 : b1; int ni1 = take ? oi1 : i1;
        float lo = take ? b1 : o1; int loi = take ? i1 : oi1;
        float c2v = take ? o2 : b2; int c2i = take ? oi2 : i2;
        bool u2 = (c2v < lo) || (c2v == lo && c2i < loi);
        b1 = n1; i1 = ni1;
        b2 = u2 ? c2v : lo; i2 = u2 ? c2i : loi;
      }
      if (l == 0) { rb1[r][w] = b1; ri1[r][w] = i1; rb2[r][w] = b2; ri2[r][w] = i2; }
    }
    __syncthreads();

    if (t < RPB) {
      float v1 = rb1[t][0], v2 = rb2[t][0]; int j1 = ri1[t][0], j2 = ri2[t][0];
      #pragma unroll
      for (int ww = 1; ww < 4; ++ww) {
        float o1 = rb1[t][ww], o2 = rb2[t][ww]; int oi1 = ri1[t][ww], oi2 = ri2[t][ww];
        bool take = (o1 < v1) || (o1 == v1 && oi1 < j1);
        float n1 = take ? o1 : v1; int ni1 = take ? oi1 : j1;
        float lo = take ? v1 : o1; int loi = take ? j1 : oi1;
        float c2v = take ? o2 : v2; int c2i = take ? oi2 : j2;
        bool u2 = (c2v < lo) || (c2v == lo && c2i < loi);
        v1 = n1; j1 = ni1; v2 = u2 ? c2v : lo; j2 = u2 ? c2i : loi;
      }
      cand[t][0] = j1; cand[t][1] = j2;
    }
    __syncthreads();

    // f64 rescore of the two candidates: wave w handles row w
    if (w < nr) {
      int c1 = cand[w][0], c2 = cand[w][1];
      float xa = xsf[l * RPB + w], xb = xsf[(l + 64) * RPB + w];
      double p1 = (double)xa * (double)embed[(size_t)c1 * DIM + l]
                + (double)xb * (double)embed[(size_t)c1 * DIM + 64 + l];
      double p2 = (double)xa * (double)embed[(size_t)c2 * DIM + l]
                + (double)xb * (double)embed[(size_t)c2 * DIM + 64 + l];
      #pragma unroll
      for (int off = 1; off < 64; off <<= 1) {
        p1 += __shfl_xor(p1, off, 64);
        p2 += __shfl_xor(p2, off, 64);
      }
      double s1 = e2d[c1] - 2.0 * p1;
      double s2 = e2d[c2] - 2.0 * p2;
      int widx = ((s2 < s1) || (s2 == s1 && c2 < c1)) ? c2 : c1;
      int row = list[base + w];
      if (l == 0) outIdx[row] = (float)widx;
      outQ[(size_t)row * DIM + l]      = embed[(size_t)widx * DIM + l];
      outQ[(size_t)row * DIM + 64 + l] = embed[(size_t)widx * DIM + 64 + l];
    }
    __syncthreads();   // xst reused next trip
  }
}

extern "C" void kernel_launch(void* const* d_in, const int* in_sizes, int n_in,
                              void* d_out, int out_size, void* d_ws, size_t ws_size,
                              hipStream_t stream) {
  const float* x     = (const float*)d_in[0];
  const float* embed = (const float*)d_in[1];
  const int N = in_sizes[0] / DIM;             // 65536 rows

  float* out    = (float*)d_out;
  float* outQ   = out;                         // [N*128] quantize
  float* outIdx = out + (size_t)N * DIM;       // [N] indices as float

  char* ws = (char*)d_ws;
  double*   e2d  = (double*)  (ws);
  float*    e2f  = (float*)   (ws + 8192);
  _Float16* eh   = (_Float16*)(ws + 12288);
  float*    eT   = (float*)   (ws + 274432);
  int*      cnt  = (int*)     (ws + 798720);
  int*      list = (int*)     (ws + 798976);

  setup_kernel  <<<NCODES / 64, 256, 0, stream>>>(embed, e2d, e2f, eh, eT, cnt);
  pass1_kernel  <<<N / TILE_M,  256, 0, stream>>>(x, embed, eh, e2f, outQ, outIdx, cnt, list);
  refine2_kernel<<<RGRID,       256, 0, stream>>>(x, embed, eT, e2d, e2f, outQ, outIdx, cnt, list);
}

// Round 15
// 275.065 us; speedup vs baseline: 1.1233x; 1.1233x over previous
//
#include <hip/hip_runtime.h>

#define DIM     128
#define NCODES  1024
#define TILE_M  64
#define FLAGThr 0.011f       // fp16 Hoeffding 0.010 + 4-bit pack err ~1.4e-5
#define RPB     4            // refine rows per block (r10-proven)
#define RGRID   1024         // refine grid (r10-proven)

typedef __attribute__((ext_vector_type(8))) _Float16 half8;
typedef __attribute__((ext_vector_type(4))) _Float16 half4;
typedef __attribute__((ext_vector_type(4))) float    f32x4;

#define AS1 __attribute__((address_space(1)))
#define AS3 __attribute__((address_space(3)))

// ws layout:
//      0 : e2d    (1024 double)          8 KB
//   8192 : e2f    (1024 float)           4 KB
//  12288 : eh     (1024*128 _Float16)  256 KB
// 274432 : embedT (128*1024 float)     512 KB
// 798720 : cnt    (int)
// 798976 : list   (65536 int)          256 KB

// -------- setup (r10 form): e2 f32/f64, eh fp16, embedT transpose ---------
__global__ __launch_bounds__(256) void setup_kernel(
    const float* __restrict__ embed, double* __restrict__ e2d,
    float* __restrict__ e2f, _Float16* __restrict__ eh,
    float* __restrict__ embedT, int* __restrict__ cnt)
{
  __shared__ float tile[64][132];            // 132: 16B-aligned rows
  __shared__ double psum[4][64];
  if (blockIdx.x == 0 && threadIdx.x == 0) *cnt = 0;
  const int c0 = blockIdx.x * 64;            // 16 blocks x 64 codes
  const int t  = threadIdx.x;

  const f32x4* E4 = (const f32x4*)(embed + (size_t)c0 * DIM);
  #pragma unroll
  for (int i = 0; i < 8; ++i) {
    int e = t + i * 256;                     // 2048 float4s = 64x128
    int r = e >> 5, c4 = e & 31;
    f32x4 v = E4[e];
    *(f32x4*)&tile[r][c4 * 4] = v;
    half4 h;
    h[0] = (_Float16)v[0]; h[1] = (_Float16)v[1];
    h[2] = (_Float16)v[2]; h[3] = (_Float16)v[3];
    *(half4*)&eh[(size_t)(c0 + r) * DIM + c4 * 4] = h;
  }
  __syncthreads();

  // e2: 4 threads per code, 32 dims each
  {
    int r = t & 63, part = t >> 6;
    double s = 0.0;
    #pragma unroll
    for (int k = 0; k < 32; ++k) {
      float v = tile[r][part * 32 + k];
      s += (double)v * v;
    }
    psum[part][r] = s;
  }
  __syncthreads();
  if (t < 64) {
    double s = psum[0][t] + psum[1][t] + psum[2][t] + psum[3][t];
    e2d[c0 + t] = s;
    e2f[c0 + t] = (float)s;
  }

  // embedT[k][c0+c] = tile[c][k]; coalesced 256B segments per k-row
  #pragma unroll
  for (int i = 0; i < 32; ++i) {
    int idx = t + i * 256;                   // 8192 = 128k x 64c
    int k = idx >> 6, c = idx & 63;
    embedT[(size_t)k * NCODES + c0 + c] = tile[c][k];
  }
}

// -------- pass1 v17: v13 pipeline VERBATIM + 4-bit pack / explicit merge --
// acc = x.e - 0.5*e2 - 16 (init in MFMA C); argmax(acc) == argmin dist.
// r14 post-mortem: v16's alo[4][4] (+64 persistent VGPRs) spilled (3rd
// confirmation: <=~15 regs headroom). v17 keeps ONLY the register-free
// half of the accuracy fix: pack 4-bit ch (not 10-bit code) into the acc
// mantissa -> pack error 1023->15 ulps (2e-3 -> 1.4e-5); full code
// reconstructed at merge (w,rl are lane constants); merge carries
// explicit (val,code) with lower-code tie-break (runs after the loop
// when afrag/vin are dead -> no loop register cost). FLAGThr 0.018 ->
// 0.011 -> flagged rows n shrink ~1.6x -> refine2 cost /1.6.
// Pipeline = v13 byte-exact (44.3us, FETCH 20.5/WRITE 33.1, VGPR 96):
// wave-private 3-deep gload_lds, counted vmcnt (8/4/0), zero loop
// barriers, swizzle involution (src col cc^rr, read col (ks*4+q)^rl).
// Exact ties (gap 0 <= FLAGThr) still flagged -> refine applies the
// reference lower-index tie-break.
__global__ __launch_bounds__(256, 2) void pass1_kernel(
    const float* __restrict__ x, const float* __restrict__ embed,
    const _Float16* __restrict__ eh, const float* __restrict__ e2f,
    float* __restrict__ outQ, float* __restrict__ outIdx,
    int* __restrict__ cnt, int* __restrict__ list)
{
  __shared__ __align__(16) _Float16 xh[TILE_M * 136];
  __shared__ __align__(16) unsigned char bbuf[4][3][4096];
  __shared__ float rb_best[4][TILE_M];
  __shared__ float rb_sec [4][TILE_M];
  __shared__ int   rb_bidx[4][TILE_M];
  __shared__ int   fidx[TILE_M];

  const int tid  = threadIdx.x;
  const int row0 = blockIdx.x * TILE_M;
  const int l  = tid & 63, w = tid >> 6;
  const int rl = l & 15,  q = l >> 4;

#define STAGE_W(CH)                                                           \
  {                                                                           \
    const char* ebase = (const char*)eh + ((size_t)(CH) * 64 + w * 16) * 256; \
    unsigned char* buf = &bbuf[w][(CH) % 3][0];                               \
    _Pragma("unroll")                                                         \
    for (int j = 0; j < 4; ++j) {                                             \
      int u  = j * 64 + l;                  /* 16B-unit 0..255 = 16r x 16c */ \
      int rr = u >> 4, cc = u & 15;                                           \
      const char* src = ebase + rr * 256 + ((cc ^ rr) * 16);                  \
      __builtin_amdgcn_global_load_lds(                                       \
          (AS1 void*)src,                                                     \
          (AS3 void*)(buf + j * 1024), 16, 0, 0);                             \
    }                                                                         \
  }

  float vin[16];                             // code(ch) = ch*64 + w*16 + rl
  #pragma unroll
  for (int g = 0; g < 16; ++g)
    vin[g] = fmaf(-0.5f, e2f[g * 64 + w * 16 + rl], -16.0f);

  {
    const f32x4* x4 = (const f32x4*)(x + (size_t)row0 * DIM);
    #pragma unroll
    for (int i = 0; i < 8; ++i) {
      int e = tid + i * 256;
      int r = e >> 5, c4 = e & 31;
      f32x4 v = x4[e];
      half4 h;
      h[0] = (_Float16)v[0]; h[1] = (_Float16)v[1];
      h[2] = (_Float16)v[2]; h[3] = (_Float16)v[3];
      *(half4*)&xh[r * 136 + c4 * 4] = h;
    }
  }
  __syncthreads();

  half8 afrag[4][4];
  #pragma unroll
  for (int m = 0; m < 4; ++m)
    #pragma unroll
    for (int ks = 0; ks < 4; ++ks)
      afrag[m][ks] = *(const half8*)&xh[(m * 16 + rl) * 136 + ks * 32 + q * 8];

  float bestp[16], secp[16];
  #pragma unroll
  for (int s = 0; s < 16; ++s) { bestp[s] = -3.0e38f; secp[s] = -3.3e38f; }

  STAGE_W(0)
  STAGE_W(1)
  STAGE_W(2)

  #pragma unroll
  for (int ch = 0; ch < 16; ++ch) {
    if (ch <= 13) {
      asm volatile("s_waitcnt vmcnt(8)" ::: "memory");
    } else if (ch == 14) {
      asm volatile("s_waitcnt vmcnt(4)" ::: "memory");
    } else {
      asm volatile("s_waitcnt vmcnt(0)" ::: "memory");
    }
    __builtin_amdgcn_sched_barrier(0);

    const unsigned char* bb = &bbuf[w][ch % 3][0];
    half8 bfrag[4];
    #pragma unroll
    for (int ks = 0; ks < 4; ++ks)
      bfrag[ks] = *(const half8*)(bb + rl * 256 + (((ks * 4 + q) ^ rl) * 16));

    const float vinit = vin[ch];
    #pragma unroll
    for (int m = 0; m < 4; ++m) {
      f32x4 acc = (f32x4){vinit, vinit, vinit, vinit};
      #pragma unroll
      for (int ks = 0; ks < 4; ++ks)
        acc = __builtin_amdgcn_mfma_f32_16x16x32_f16(afrag[m][ks], bfrag[ks], acc, 0, 0, 0);
      #pragma unroll
      for (int r = 0; r < 4; ++r) {
        const int s = m * 4 + r;
        // pack ONLY ch (4 bits); w,rl reconstructed at merge
        float scp = __int_as_float((__float_as_int(acc[r]) & ~15) | ch);
        secp[s]  = __builtin_amdgcn_fmed3f(scp, bestp[s], secp[s]);
        bestp[s] = fmaxf(bestp[s], scp);
      }
    }

    if (ch + 3 < 16) {
      asm volatile("s_waitcnt lgkmcnt(0)" ::: "memory");
      __builtin_amdgcn_sched_barrier(0);
      STAGE_W(ch + 3)
    }
  }
#undef STAGE_W

  // unpack (strip 4-bit tag, recover full codes), explicit-index merges
  float bval[16], sval[16];
  int   bcode[16];
  #pragma unroll
  for (int s = 0; s < 16; ++s) {
    int bi = __float_as_int(bestp[s]);
    bval[s]  = __int_as_float(bi & ~15);
    bcode[s] = (bi & 15) * 64 + w * 16 + rl;
    sval[s]  = __int_as_float(__float_as_int(secp[s]) & ~15);
  }
  // merge across the 16 lanes of each quarter; ties -> lower code
  #pragma unroll
  for (int off = 1; off < 16; off <<= 1) {
    #pragma unroll
    for (int s = 0; s < 16; ++s) {
      float ov = __shfl_xor(bval[s],  off, 16);
      int   oc = __shfl_xor(bcode[s], off, 16);
      float os = __shfl_xor(sval[s],  off, 16);
      bool take = (ov > bval[s]) || (ov == bval[s] && oc < bcode[s]);
      float lose = take ? bval[s] : ov;
      float cs   = take ? os : sval[s];
      bval[s]  = take ? ov : bval[s];
      bcode[s] = take ? oc : bcode[s];
      sval[s]  = fmaxf(cs, lose);
    }
  }
  if (rl == 0) {
    #pragma unroll
    for (int m = 0; m < 4; ++m)
      #pragma unroll
      for (int r = 0; r < 4; ++r) {
        int s = m * 4 + r;
        int row = m * 16 + q * 4 + r;
        rb_best[w][row] = bval[s];
        rb_bidx[w][row] = bcode[s];
        rb_sec [w][row] = sval[s];
      }
  }
  __syncthreads();

  // merge the 4 waves (disjoint code sets), emit index + flag near-ties
  if (tid < TILE_M) {
    float bv = rb_best[0][tid]; int bc = rb_bidx[0][tid]; float sv = rb_sec[0][tid];
    #pragma unroll
    for (int ww = 1; ww < 4; ++ww) {
      float ob = rb_best[ww][tid]; int oc = rb_bidx[ww][tid]; float os = rb_sec[ww][tid];
      bool take = (ob > bv) || (ob == bv && oc < bc);
      float lose = take ? bv : ob;
      float cs   = take ? os : sv;
      bv = take ? ob : bv;
      bc = take ? oc : bc;
      sv = fmaxf(cs, lose);
    }
    int grow = row0 + tid;
    outIdx[grow] = (float)bc;
    fidx[tid] = bc;
    if (bv - sv <= FLAGThr) {
      int p = atomicAdd(cnt, 1);
      list[p] = grow;
    }
  }
  __syncthreads();

  // gather quantize = embed[idx] (coalesced writes, L2-hot embed reads)
  {
    const f32x4* E4   = (const f32x4*)embed;
    f32x4*       out4 = (f32x4*)(outQ + (size_t)row0 * DIM);
    #pragma unroll
    for (int i = 0; i < 8; ++i) {
      int e = tid + i * 256;
      int r = e >> 5, c4 = e & 31;
      out4[e] = E4[fidx[r] * 32 + c4];
    }
  }
}

// -------- refine v2 (r10 form): coalesced f32 rescan via embedT, f64 ------
__global__ __launch_bounds__(256) void refine2_kernel(
    const float* __restrict__ x, const float* __restrict__ embed,
    const float* __restrict__ embedT,
    const double* __restrict__ e2d, const float* __restrict__ e2f,
    float* __restrict__ outQ, float* __restrict__ outIdx,
    const int* __restrict__ cnt, const int* __restrict__ list)
{
  __shared__ f32x4 xst[DIM];                 // xst[k][r]: k-th dim of row r
  __shared__ float rb1[RPB][4], rb2[RPB][4];
  __shared__ int   ri1[RPB][4], ri2[RPB][4];
  __shared__ int   cand[RPB][2];

  const int t = threadIdx.x;
  const int l = t & 63, w = t >> 6;
  const int n = *cnt;
  float* xsf = (float*)xst;

  for (int base = blockIdx.x * RPB; base < n; base += RGRID * RPB) {
    const int nr = min(RPB, n - base);
    // stage rows (transposed: xst[k][r])
    #pragma unroll
    for (int i = 0; i < 2; ++i) {
      int idx = t + i * 256;
      int r = idx >> 7, k = idx & 127;
      float v = 0.f;
      if (r < nr) v = x[(size_t)list[base + r] * DIM + k];
      xsf[k * RPB + r] = v;
    }
    __syncthreads();

    // thread t owns codes 4t..4t+3; fully coalesced embedT stream
    f32x4 dot[RPB];
    #pragma unroll
    for (int r = 0; r < RPB; ++r) dot[r] = (f32x4){0.f, 0.f, 0.f, 0.f};
    const f32x4* eT4 = (const f32x4*)embedT;
    #pragma unroll 4
    for (int k = 0; k < DIM; ++k) {
      f32x4 e4  = eT4[k * 256 + t];
      f32x4 xk4 = xst[k];
      #pragma unroll
      for (int r = 0; r < RPB; ++r) {
        dot[r][0] = fmaf(xk4[r], e4[0], dot[r][0]);
        dot[r][1] = fmaf(xk4[r], e4[1], dot[r][1]);
        dot[r][2] = fmaf(xk4[r], e4[2], dot[r][2]);
        dot[r][3] = fmaf(xk4[r], e4[3], dot[r][3]);
      }
    }

    // per-thread top-2 over its 4 codes, then wave + block merges
    #pragma unroll
    for (int r = 0; r < RPB; ++r) {
      float b1 = 3.4e38f, b2 = 3.4e38f; int i1 = 0, i2 = 0;
      #pragma unroll
      for (int j = 0; j < 4; ++j) {
        int c = 4 * t + j;
        float sc = fmaf(-2.0f, dot[r][j], e2f[c]);
        bool better = (sc < b1);                 // ties keep lower index
        float lv = better ? b1 : sc;  int li = better ? i1 : c;
        if (better) { b1 = sc; i1 = c; }
        bool t2 = (lv < b2) || (lv == b2 && li < i2);
        if (t2) { b2 = lv; i2 = li; }
      }
      #pragma unroll
      for (int off = 1; off < 64; off <<= 1) {
        float o1 = __shfl_xor(b1, off, 64); int oi1 = __shfl_xor(i1, off, 64);
        float o2 = __shfl_xor(b2, off, 64); int oi2 = __shfl_xor(i2, off, 64);
        bool take = (o1 < b1) || (o1 == b1 && oi1 < i1);
        float n1 = take ? o1 : b1; int ni1 = take ? oi1 : i1;
        float lo = take ? b1 : o1; int loi = take ? i1 : oi1;
        float c2v = take ? o2 : b2; int c2i = take ? oi2 : i2;
        bool u2 = (c2v < lo) || (c2v == lo && c2i < loi);
        b1 = n1; i1 = ni1;
        b2 = u2 ? c2v : lo; i2 = u2 ? c2i : loi;
      }
      if (l == 0) { rb1[r][w] = b1; ri1[r][w] = i1; rb2[r][w] = b2; ri2[r][w] = i2; }
    }
    __syncthreads();

    if (t < RPB) {
      float v1 = rb1[t][0], v2 = rb2[t][0]; int j1 = ri1[t][0], j2 = ri2[t][0];
      #pragma unroll
      for (int ww = 1; ww < 4; ++ww) {
        float o1 = rb1[t][ww], o2 = rb2[t][ww]; int oi1 = ri1[t][ww], oi2 = ri2[t][ww];
        bool take = (o1 < v1) || (o1 == v1 && oi1 < j1);
        float n1 = take ? o1 : v1; int ni1 = take ? oi1 : j1;
        float lo = take ? v1 : o1; int loi = take ? j1 : oi1;
        float c2v = take ? o2 : v2; int c2i = take ? oi2 : j2;
        bool u2 = (c2v < lo) || (c2v == lo && c2i < loi);
        v1 = n1; j1 = ni1; v2 = u2 ? c2v : lo; j2 = u2 ? c2i : loi;
      }
      cand[t][0] = j1; cand[t][1] = j2;
    }
    __syncthreads();

    // f64 rescore of the two candidates: wave w handles row w
    if (w < nr) {
      int c1 = cand[w][0], c2 = cand[w][1];
      float xa = xsf[l * RPB + w], xb = xsf[(l + 64) * RPB + w];
      double p1 = (double)xa * (double)embed[(size_t)c1 * DIM + l]
                + (double)xb * (double)embed[(size_t)c1 * DIM + 64 + l];
      double p2 = (double)xa * (double)embed[(size_t)c2 * DIM + l]
                + (double)xb * (double)embed[(size_t)c2 * DIM + 64 + l];
      #pragma unroll
      for (int off = 1; off < 64; off <<= 1) {
        p1 += __shfl_xor(p1, off, 64);
        p2 += __shfl_xor(p2, off, 64);
      }
      double s1 = e2d[c1] - 2.0 * p1;
      double s2 = e2d[c2] - 2.0 * p2;
      int widx = ((s2 < s1) || (s2 == s1 && c2 < c1)) ? c2 : c1;
      int row = list[base + w];
      if (l == 0) outIdx[row] = (float)widx;
      outQ[(size_t)row * DIM + l]      = embed[(size_t)widx * DIM + l];
      outQ[(size_t)row * DIM + 64 + l] = embed[(size_t)widx * DIM + 64 + l];
    }
    __syncthreads();   // xst reused next trip
  }
}

extern "C" void kernel_launch(void* const* d_in, const int* in_sizes, int n_in,
                              void* d_out, int out_size, void* d_ws, size_t ws_size,
                              hipStream_t stream) {
  const float* x     = (const float*)d_in[0];
  const float* embed = (const float*)d_in[1];
  const int N = in_sizes[0] / DIM;             // 65536 rows

  float* out    = (float*)d_out;
  float* outQ   = out;                         // [N*128] quantize
  float* outIdx = out + (size_t)N * DIM;       // [N] indices as float

  char* ws = (char*)d_ws;
  double*   e2d  = (double*)  (ws);
  float*    e2f  = (float*)   (ws + 8192);
  _Float16* eh   = (_Float16*)(ws + 12288);
  float*    eT   = (float*)   (ws + 274432);
  int*      cnt  = (int*)     (ws + 798720);
  int*      list = (int*)     (ws + 798976);

  setup_kernel  <<<NCODES / 64, 256, 0, stream>>>(embed, e2d, e2f, eh, eT, cnt);
  pass1_kernel  <<<N / TILE_M,  256, 0, stream>>>(x, embed, eh, e2f, outQ, outIdx, cnt, list);
  refine2_kernel<<<RGRID,       256, 0, stream>>>(x, embed, eT, e2d, e2f, outQ, outIdx, cnt, list);
}

// Round 16
// 132.893 us; speedup vs baseline: 2.3250x; 2.0698x over previous
//
#include <hip/hip_runtime.h>

#define DIM     128
#define NCODES  1024
#define TILE_M  64
#define FLAGThr 0.012f       // fp16 Hoeffding 0.010 + 8-bit pack err 0.002
#define RPB     4            // refine rows per block (r10-proven)
#define RGRID   1024         // refine grid (r10-proven)

typedef __attribute__((ext_vector_type(8))) _Float16 half8;
typedef __attribute__((ext_vector_type(4))) _Float16 half4;
typedef __attribute__((ext_vector_type(4))) float    f32x4;

#define AS1 __attribute__((address_space(1)))
#define AS3 __attribute__((address_space(3)))

// ws layout:
//      0 : e2d    (1024 double)          8 KB
//   8192 : e2f    (1024 float)           4 KB
//  12288 : eh     (1024*128 _Float16)  256 KB
// 274432 : embedT (128*1024 float)     512 KB
// 798720 : cnt    (int)
// 798976 : list   (65536 int)          256 KB

// -------- setup (r10 form): e2 f32/f64, eh fp16, embedT transpose ---------
__global__ __launch_bounds__(256) void setup_kernel(
    const float* __restrict__ embed, double* __restrict__ e2d,
    float* __restrict__ e2f, _Float16* __restrict__ eh,
    float* __restrict__ embedT, int* __restrict__ cnt)
{
  __shared__ float tile[64][132];            // 132: 16B-aligned rows
  __shared__ double psum[4][64];
  if (blockIdx.x == 0 && threadIdx.x == 0) *cnt = 0;
  const int c0 = blockIdx.x * 64;            // 16 blocks x 64 codes
  const int t  = threadIdx.x;

  const f32x4* E4 = (const f32x4*)(embed + (size_t)c0 * DIM);
  #pragma unroll
  for (int i = 0; i < 8; ++i) {
    int e = t + i * 256;                     // 2048 float4s = 64x128
    int r = e >> 5, c4 = e & 31;
    f32x4 v = E4[e];
    *(f32x4*)&tile[r][c4 * 4] = v;
    half4 h;
    h[0] = (_Float16)v[0]; h[1] = (_Float16)v[1];
    h[2] = (_Float16)v[2]; h[3] = (_Float16)v[3];
    *(half4*)&eh[(size_t)(c0 + r) * DIM + c4 * 4] = h;
  }
  __syncthreads();

  // e2: 4 threads per code, 32 dims each
  {
    int r = t & 63, part = t >> 6;
    double s = 0.0;
    #pragma unroll
    for (int k = 0; k < 32; ++k) {
      float v = tile[r][part * 32 + k];
      s += (double)v * v;
    }
    psum[part][r] = s;
  }
  __syncthreads();
  if (t < 64) {
    double s = psum[0][t] + psum[1][t] + psum[2][t] + psum[3][t];
    e2d[c0 + t] = s;
    e2f[c0 + t] = (float)s;
  }

  // embedT[k][c0+c] = tile[c][k]; coalesced 256B segments per k-row
  #pragma unroll
  for (int i = 0; i < 32; ++i) {
    int idx = t + i * 256;                   // 8192 = 128k x 64c
    int k = idx >> 6, c = idx & 63;
    embedT[(size_t)k * NCODES + c0 + c] = tile[c][k];
  }
}

// -------- pass1 v18: v13 structure VERBATIM, 8-bit tag (ch*16+rl) ---------
// acc = x.e - 0.5*e2 - 16 (init in MFMA C); argmax(acc) == argmin dist.
// r15 post-mortem: v17's 3-array explicit merge (48 regs + temps) spilled;
// v13's packed 2-array merge (32 regs) is the proven-clean form. v18 keeps
// v13's loop AND merge byte-identical, only the tag changes: 8-bit
// tag = ch*16 + rl (self-contained within the 16-lane merge group, where
// rl is the only lane-varying code part). Pack err 1023->255 ulps
// (0.008->0.002 budget) -> FLAGThr 0.018->0.012 -> flagged rows n
// shrink ~1.5x -> refine2 cost -33%. Unpack at rl==0 only (in-place, no
// arrays): code = ((bi>>4)&15)*64 + w*16 + (bi&15). Final 4-way merge
// explicit (val,code). Ties (gap 0 <= thr) still flagged -> refine
// applies the reference lower-index tie-break (pack tie direction moot).
// Pipeline: wave-private 3-deep gload_lds, counted vmcnt (8/4/0), zero
// loop barriers, swizzle involution. Target: VGPR ~96, FETCH ~20.5/WRITE
// ~33 MB, 44-46us (WRITE>45MB => spilled => revert to r10 verbatim).
__global__ __launch_bounds__(256, 2) void pass1_kernel(
    const float* __restrict__ x, const float* __restrict__ embed,
    const _Float16* __restrict__ eh, const float* __restrict__ e2f,
    float* __restrict__ outQ, float* __restrict__ outIdx,
    int* __restrict__ cnt, int* __restrict__ list)
{
  __shared__ __align__(16) _Float16 xh[TILE_M * 136];
  __shared__ __align__(16) unsigned char bbuf[4][3][4096];
  __shared__ float rb_best[4][TILE_M];
  __shared__ float rb_sec [4][TILE_M];
  __shared__ int   rb_bidx[4][TILE_M];
  __shared__ int   fidx[TILE_M];

  const int tid  = threadIdx.x;
  const int row0 = blockIdx.x * TILE_M;
  const int l  = tid & 63, w = tid >> 6;
  const int rl = l & 15,  q = l >> 4;

#define STAGE_W(CH)                                                           \
  {                                                                           \
    const char* ebase = (const char*)eh + ((size_t)(CH) * 64 + w * 16) * 256; \
    unsigned char* buf = &bbuf[w][(CH) % 3][0];                               \
    _Pragma("unroll")                                                         \
    for (int j = 0; j < 4; ++j) {                                             \
      int u  = j * 64 + l;                  /* 16B-unit 0..255 = 16r x 16c */ \
      int rr = u >> 4, cc = u & 15;                                           \
      const char* src = ebase + rr * 256 + ((cc ^ rr) * 16);                  \
      __builtin_amdgcn_global_load_lds(                                       \
          (AS1 void*)src,                                                     \
          (AS3 void*)(buf + j * 1024), 16, 0, 0);                             \
    }                                                                         \
  }

  float vin[16];                             // code(ch) = ch*64 + w*16 + rl
  #pragma unroll
  for (int g = 0; g < 16; ++g)
    vin[g] = fmaf(-0.5f, e2f[g * 64 + w * 16 + rl], -16.0f);

  {
    const f32x4* x4 = (const f32x4*)(x + (size_t)row0 * DIM);
    #pragma unroll
    for (int i = 0; i < 8; ++i) {
      int e = tid + i * 256;
      int r = e >> 5, c4 = e & 31;
      f32x4 v = x4[e];
      half4 h;
      h[0] = (_Float16)v[0]; h[1] = (_Float16)v[1];
      h[2] = (_Float16)v[2]; h[3] = (_Float16)v[3];
      *(half4*)&xh[r * 136 + c4 * 4] = h;
    }
  }
  __syncthreads();

  half8 afrag[4][4];
  #pragma unroll
  for (int m = 0; m < 4; ++m)
    #pragma unroll
    for (int ks = 0; ks < 4; ++ks)
      afrag[m][ks] = *(const half8*)&xh[(m * 16 + rl) * 136 + ks * 32 + q * 8];

  float bestp[16], secp[16];
  #pragma unroll
  for (int s = 0; s < 16; ++s) { bestp[s] = -3.0e38f; secp[s] = -3.3e38f; }

  STAGE_W(0)
  STAGE_W(1)
  STAGE_W(2)

  #pragma unroll
  for (int ch = 0; ch < 16; ++ch) {
    if (ch <= 13) {
      asm volatile("s_waitcnt vmcnt(8)" ::: "memory");
    } else if (ch == 14) {
      asm volatile("s_waitcnt vmcnt(4)" ::: "memory");
    } else {
      asm volatile("s_waitcnt vmcnt(0)" ::: "memory");
    }
    __builtin_amdgcn_sched_barrier(0);

    const unsigned char* bb = &bbuf[w][ch % 3][0];
    half8 bfrag[4];
    #pragma unroll
    for (int ks = 0; ks < 4; ++ks)
      bfrag[ks] = *(const half8*)(bb + rl * 256 + (((ks * 4 + q) ^ rl) * 16));

    const float vinit = vin[ch];
    const int tag = ch * 16 + rl;            // 8-bit, merge-group complete
    #pragma unroll
    for (int m = 0; m < 4; ++m) {
      f32x4 acc = (f32x4){vinit, vinit, vinit, vinit};
      #pragma unroll
      for (int ks = 0; ks < 4; ++ks)
        acc = __builtin_amdgcn_mfma_f32_16x16x32_f16(afrag[m][ks], bfrag[ks], acc, 0, 0, 0);
      #pragma unroll
      for (int r = 0; r < 4; ++r) {
        const int s = m * 4 + r;
        float scp = __int_as_float((__float_as_int(acc[r]) & ~255) | tag);
        secp[s]  = __builtin_amdgcn_fmed3f(scp, bestp[s], secp[s]);
        bestp[s] = fmaxf(bestp[s], scp);
      }
    }

    if (ch + 3 < 16) {
      asm volatile("s_waitcnt lgkmcnt(0)" ::: "memory");
      __builtin_amdgcn_sched_barrier(0);
      STAGE_W(ch + 3)
    }
  }
#undef STAGE_W

  // merge across the 16 lanes of each quarter — v13's packed form verbatim
  #pragma unroll
  for (int off = 1; off < 16; off <<= 1) {
    #pragma unroll
    for (int s = 0; s < 16; ++s) {
      float ob = __shfl_xor(bestp[s], off, 16);
      float os = __shfl_xor(secp[s],  off, 16);
      secp[s]  = fmaxf(__builtin_amdgcn_fmed3f(bestp[s], ob, secp[s]), os);
      bestp[s] = fmaxf(bestp[s], ob);
    }
  }
  // unpack at rl==0 only (in-place, no arrays): tag -> full code
  if (rl == 0) {
    #pragma unroll
    for (int m = 0; m < 4; ++m)
      #pragma unroll
      for (int r = 0; r < 4; ++r) {
        int s = m * 4 + r;
        int row = m * 16 + q * 4 + r;
        int bi = __float_as_int(bestp[s]);
        rb_best[w][row] = __int_as_float(bi & ~255);
        rb_bidx[w][row] = ((bi >> 4) & 15) * 64 + w * 16 + (bi & 15);
        rb_sec [w][row] = __int_as_float(__float_as_int(secp[s]) & ~255);
      }
  }
  __syncthreads();

  // merge the 4 waves (disjoint code sets), emit index + flag near-ties
  if (tid < TILE_M) {
    float bv = rb_best[0][tid]; int bc = rb_bidx[0][tid]; float sv = rb_sec[0][tid];
    #pragma unroll
    for (int ww = 1; ww < 4; ++ww) {
      float ob = rb_best[ww][tid]; int oc = rb_bidx[ww][tid]; float os = rb_sec[ww][tid];
      bool take = (ob > bv) || (ob == bv && oc < bc);
      float lose = take ? bv : ob;
      float cs   = take ? os : sv;
      bv = take ? ob : bv;
      bc = take ? oc : bc;
      sv = fmaxf(cs, lose);
    }
    int grow = row0 + tid;
    outIdx[grow] = (float)bc;
    fidx[tid] = bc;
    if (bv - sv <= FLAGThr) {
      int p = atomicAdd(cnt, 1);
      list[p] = grow;
    }
  }
  __syncthreads();

  // gather quantize = embed[idx] (coalesced writes, L2-hot embed reads)
  {
    const f32x4* E4   = (const f32x4*)embed;
    f32x4*       out4 = (f32x4*)(outQ + (size_t)row0 * DIM);
    #pragma unroll
    for (int i = 0; i < 8; ++i) {
      int e = tid + i * 256;
      int r = e >> 5, c4 = e & 31;
      out4[e] = E4[fidx[r] * 32 + c4];
    }
  }
}

// -------- refine v2 (r10 form): coalesced f32 rescan via embedT, f64 ------
__global__ __launch_bounds__(256) void refine2_kernel(
    const float* __restrict__ x, const float* __restrict__ embed,
    const float* __restrict__ embedT,
    const double* __restrict__ e2d, const float* __restrict__ e2f,
    float* __restrict__ outQ, float* __restrict__ outIdx,
    const int* __restrict__ cnt, const int* __restrict__ list)
{
  __shared__ f32x4 xst[DIM];                 // xst[k][r]: k-th dim of row r
  __shared__ float rb1[RPB][4], rb2[RPB][4];
  __shared__ int   ri1[RPB][4], ri2[RPB][4];
  __shared__ int   cand[RPB][2];

  const int t = threadIdx.x;
  const int l = t & 63, w = t >> 6;
  const int n = *cnt;
  float* xsf = (float*)xst;

  for (int base = blockIdx.x * RPB; base < n; base += RGRID * RPB) {
    const int nr = min(RPB, n - base);
    // stage rows (transposed: xst[k][r])
    #pragma unroll
    for (int i = 0; i < 2; ++i) {
      int idx = t + i * 256;
      int r = idx >> 7, k = idx & 127;
      float v = 0.f;
      if (r < nr) v = x[(size_t)list[base + r] * DIM + k];
      xsf[k * RPB + r] = v;
    }
    __syncthreads();

    // thread t owns codes 4t..4t+3; fully coalesced embedT stream
    f32x4 dot[RPB];
    #pragma unroll
    for (int r = 0; r < RPB; ++r) dot[r] = (f32x4){0.f, 0.f, 0.f, 0.f};
    const f32x4* eT4 = (const f32x4*)embedT;
    #pragma unroll 4
    for (int k = 0; k < DIM; ++k) {
      f32x4 e4  = eT4[k * 256 + t];
      f32x4 xk4 = xst[k];
      #pragma unroll
      for (int r = 0; r < RPB; ++r) {
        dot[r][0] = fmaf(xk4[r], e4[0], dot[r][0]);
        dot[r][1] = fmaf(xk4[r], e4[1], dot[r][1]);
        dot[r][2] = fmaf(xk4[r], e4[2], dot[r][2]);
        dot[r][3] = fmaf(xk4[r], e4[3], dot[r][3]);
      }
    }

    // per-thread top-2 over its 4 codes, then wave + block merges
    #pragma unroll
    for (int r = 0; r < RPB; ++r) {
      float b1 = 3.4e38f, b2 = 3.4e38f; int i1 = 0, i2 = 0;
      #pragma unroll
      for (int j = 0; j < 4; ++j) {
        int c = 4 * t + j;
        float sc = fmaf(-2.0f, dot[r][j], e2f[c]);
        bool better = (sc < b1);                 // ties keep lower index
        float lv = better ? b1 : sc;  int li = better ? i1 : c;
        if (better) { b1 = sc; i1 = c; }
        bool t2 = (lv < b2) || (lv == b2 && li < i2);
        if (t2) { b2 = lv; i2 = li; }
      }
      #pragma unroll
      for (int off = 1; off < 64; off <<= 1) {
        float o1 = __shfl_xor(b1, off, 64); int oi1 = __shfl_xor(i1, off, 64);
        float o2 = __shfl_xor(b2, off, 64); int oi2 = __shfl_xor(i2, off, 64);
        bool take = (o1 < b1) || (o1 == b1 && oi1 < i1);
        float n1 = take ? o1 : b1; int ni1 = take ? oi1 : i1;
        float lo = take ? b1 : o1; int loi = take ? i1 : oi1;
        float c2v = take ? o2 : b2; int c2i = take ? oi2 : i2;
        bool u2 = (c2v < lo) || (c2v == lo && c2i < loi);
        b1 = n1; i1 = ni1;
        b2 = u2 ? c2v : lo; i2 = u2 ? c2i : loi;
      }
      if (l == 0) { rb1[r][w] = b1; ri1[r][w] = i1; rb2[r][w] = b2; ri2[r][w] = i2; }
    }
    __syncthreads();

    if (t < RPB) {
      float v1 = rb1[t][0], v2 = rb2[t][0]; int j1 = ri1[t][0], j2 = ri2[t][0];
      #pragma unroll
      for (int ww = 1; ww < 4; ++ww) {
        float o1 = rb1[t][ww], o2 = rb2[t][ww]; int oi1 = ri1[t][ww], oi2 = ri2[t][ww];
        bool take = (o1 < v1) || (o1 == v1 && oi1 < j1);
        float n1 = take ? o1 : v1; int ni1 = take ? oi1 : j1;
        float lo = take ? v1 : o1; int loi = take ? j1 : oi1;
        float c2v = take ? o2 : v2; int c2i = take ? oi2 : j2;
        bool u2 = (c2v < lo) || (c2v == lo && c2i < loi);
        v1 = n1; j1 = ni1; v2 = u2 ? c2v : lo; j2 = u2 ? c2i : loi;
      }
      cand[t][0] = j1; cand[t][1] = j2;
    }
    __syncthreads();

    // f64 rescore of the two candidates: wave w handles row w
    if (w < nr) {
      int c1 = cand[w][0], c2 = cand[w][1];
      float xa = xsf[l * RPB + w], xb = xsf[(l + 64) * RPB + w];
      double p1 = (double)xa * (double)embed[(size_t)c1 * DIM + l]
                + (double)xb * (double)embed[(size_t)c1 * DIM + 64 + l];
      double p2 = (double)xa * (double)embed[(size_t)c2 * DIM + l]
                + (double)xb * (double)embed[(size_t)c2 * DIM + 64 + l];
      #pragma unroll
      for (int off = 1; off < 64; off <<= 1) {
        p1 += __shfl_xor(p1, off, 64);
        p2 += __shfl_xor(p2, off, 64);
      }
      double s1 = e2d[c1] - 2.0 * p1;
      double s2 = e2d[c2] - 2.0 * p2;
      int widx = ((s2 < s1) || (s2 == s1 && c2 < c1)) ? c2 : c1;
      int row = list[base + w];
      if (l == 0) outIdx[row] = (float)widx;
      outQ[(size_t)row * DIM + l]      = embed[(size_t)widx * DIM + l];
      outQ[(size_t)row * DIM + 64 + l] = embed[(size_t)widx * DIM + 64 + l];
    }
    __syncthreads();   // xst reused next trip
  }
}

extern "C" void kernel_launch(void* const* d_in, const int* in_sizes, int n_in,
                              void* d_out, int out_size, void* d_ws, size_t ws_size,
                              hipStream_t stream) {
  const float* x     = (const float*)d_in[0];
  const float* embed = (const float*)d_in[1];
  const int N = in_sizes[0] / DIM;             // 65536 rows

  float* out    = (float*)d_out;
  float* outQ   = out;                         // [N*128] quantize
  float* outIdx = out + (size_t)N * DIM;       // [N] indices as float

  char* ws = (char*)d_ws;
  double*   e2d  = (double*)  (ws);
  float*    e2f  = (float*)   (ws + 8192);
  _Float16* eh   = (_Float16*)(ws + 12288);
  float*    eT   = (float*)   (ws + 274432);
  int*      cnt  = (int*)     (ws + 798720);
  int*      list = (int*)     (ws + 798976);

  setup_kernel  <<<NCODES / 64, 256, 0, stream>>>(embed, e2d, e2f, eh, eT, cnt);
  pass1_kernel  <<<N / TILE_M,  256, 0, stream>>>(x, embed, eh, e2f, outQ, outIdx, cnt, list);
  refine2_kernel<<<RGRID,       256, 0, stream>>>(x, embed, eT, e2d, e2f, outQ, outIdx, cnt, list);
}